// Round 15
// baseline (202.957 us; speedup 1.0000x reference)
//
#include <hip/hip_runtime.h>
#include <math.h>

#define N_NODES 50000
#define N_EDGES 800000
#define F_IN    256
#define H_DIM   128
#define D_DIM   64
#define MAX_LOGSTD 10.0f
#define LEAKY_SLOPE 0.01f

#define NB       196            // dst buckets (dst>>8)
#define BCAP     5000           // per-bucket staging capacity (mean 4082, +14 sigma)
#define GEMM_BLK 782            // ceil(N_NODES/64)

using bf16x8 = __attribute__((ext_vector_type(8))) short;
using f32x4  = __attribute__((ext_vector_type(4))) float;
using f32x2  = __attribute__((ext_vector_type(2))) float;

// ---------- bf16 helpers (RNE pack, shift unpack) ----------
__device__ inline float bflo(unsigned u) { return __uint_as_float(u << 16); }
__device__ inline float bfhi(unsigned u) { return __uint_as_float(u & 0xFFFF0000u); }
__device__ inline unsigned short f2bf(float f) {
    unsigned u = __float_as_uint(f);
    u += 0x7FFFu + ((u >> 16) & 1u);
    return (unsigned short)(u >> 16);
}
__device__ inline unsigned pack2(float a, float b) {
    return (unsigned)f2bf(a) | ((unsigned)f2bf(b) << 16);
}
__device__ inline f32x2 up2(unsigned u) {
    f32x2 r;
    r.x = __uint_as_float(u << 16);
    r.y = __uint_as_float(u & 0xFFFF0000u);
    return r;
}
__device__ inline float red16(float d) {
    d += __shfl_xor(d, 1); d += __shfl_xor(d, 2);
    d += __shfl_xor(d, 4); d += __shfl_xor(d, 8);
    return d;
}

// ======= prepM: M = Wq@Wk^T/8 (128x128 per conv), b' = bq@Wk^T/8 =======
__global__ void k_prepM(const float* __restrict__ Wq0, const float* __restrict__ Wk0,
                        const float* __restrict__ bq0,
                        const float* __restrict__ Wq1, const float* __restrict__ Wk1,
                        const float* __restrict__ bq1,
                        float* __restrict__ Mf, float* __restrict__ bpm,
                        float* __restrict__ bpl) {
    int blk = blockIdx.x, t = threadIdx.x;
    if (blk < 128) {
        int tid = blk * 256 + t;          // 0..32767
        int conv = tid >> 14;
        int rem = tid & 16383;
        int i = rem >> 7, jj = rem & 127;
        const float* Wq = conv ? Wq1 : Wq0;
        const float* Wk = conv ? Wk1 : Wk0;
        float s = 0.f;
#pragma unroll 8
        for (int n = 0; n < 64; ++n) s = fmaf(Wq[i * 64 + n], Wk[jj * 64 + n], s);
        Mf[conv * 16384 + i * 128 + jj] = s * 0.125f;
    } else {
        int jj = t & 127;
        int conv = t >> 7;
        const float* Wk = conv ? Wk1 : Wk0;
        const float* bq = conv ? bq1 : bq0;
        float s = 0.f;
#pragma unroll 8
        for (int n = 0; n < 64; ++n) s = fmaf(bq[n], Wk[jj * 64 + n], s);
        if (conv) bpl[jj] = s * 0.125f; else bpm[jj] = s * 0.125f;
    }
}

// ======= prep: weight fragment shuffles (wfg, wfp 6 slots, wfv 2 slots) + init =======
__global__ void k_prep(const float* __restrict__ Wg, const float* __restrict__ Mf,
                       const float* __restrict__ Ws0, const float* __restrict__ Ws1,
                       const float* __restrict__ Wv0, const float* __restrict__ Wv1,
                       unsigned short* __restrict__ wfg, unsigned short* __restrict__ wfp,
                       unsigned short* __restrict__ wfv, int* __restrict__ gCursor) {
    int blk = blockIdx.x, t = threadIdx.x;
    if (blk == 384) { if (t < 256) gCursor[t] = 0; return; }
    if (blk < 128) {
        int tid = blk * 256 + t;
        int j = tid & 7, ct = (tid >> 3) & 1, ks = (tid >> 4) & 7;
        int l = (tid >> 7) & 63, w = tid >> 13;
        int k = ks * 32 + (l >> 4) * 8 + j;
        int n = w * 32 + ct * 16 + (l & 15);
        wfg[tid] = f2bf(Wg[k * H_DIM + n]);
    } else if (blk < 320) {
        // wfp: slots 0,1: M_mu halves; 2: Ws_mu; 3,4: M_ls halves; 5: Ws_ls. K=128.
        int tid = (blk - 128) * 256 + t;   // 0..49151
        int j = tid & 7, ct = (tid >> 3) & 3, ks = (tid >> 5) & 3;
        int l = (tid >> 7) & 63, w = tid >> 13;
        int k = ks * 32 + (l >> 4) * 8 + j;
        int n = ct * 16 + (l & 15);
        float val;
        if (w == 2)      val = Ws0[k * D_DIM + n];
        else if (w == 5) val = Ws1[k * D_DIM + n];
        else {
            int conv = (w >= 3);
            int half = conv ? (w - 3) : w;
            val = Mf[conv * 16384 + k * 128 + half * 64 + n];
        }
        wfp[tid] = f2bf(val);
    } else {
        // wfv: slot 0: Wv_mu, slot 1: Wv_ls (128x64)
        int tid = (blk - 320) * 256 + t;   // 0..16383
        int j = tid & 7, ct = (tid >> 3) & 3, ks = (tid >> 5) & 3;
        int l = (tid >> 7) & 63, w = tid >> 13;
        int k = ks * 32 + (l >> 4) * 8 + j;
        int n = ct * 16 + (l & 15);
        const float* Wv = w ? Wv1 : Wv0;
        wfv[tid] = f2bf(Wv[k * D_DIM + n]);
    }
}

// ======= CSR phase A: bucket edges into contiguous staging chunks =======
__global__ __launch_bounds__(256) void k_bucketA(
        const int* __restrict__ src, const int* __restrict__ dst,
        int* __restrict__ gCursor, uint2* __restrict__ staging) {
    __shared__ int cnt[NB];
    __shared__ int base[NB];
    int t = threadIdx.x;
    int e0 = blockIdx.x * 4096;
    for (int i = t; i < NB; i += 256) cnt[i] = 0;
    __syncthreads();
    int s[16], d[16], b[16];
#pragma unroll
    for (int i = 0; i < 16; ++i) {
        int e = e0 + t + i * 256;
        if (e < N_EDGES) {
            s[i] = src[e]; d[i] = dst[e]; b[i] = d[i] >> 8;
            atomicAdd(&cnt[b[i]], 1);
        } else b[i] = -1;
    }
    __syncthreads();
    for (int i = t; i < NB; i += 256) base[i] = atomicAdd(&gCursor[i], cnt[i]);
    __syncthreads();
    for (int i = t; i < NB; i += 256) cnt[i] = 0;
    __syncthreads();
#pragma unroll
    for (int i = 0; i < 16; ++i) {
        if (b[i] >= 0) {
            int lp = atomicAdd(&cnt[b[i]], 1);
            staging[(size_t)b[i] * BCAP + base[b[i]] + lp] =
                make_uint2((unsigned)s[i], (unsigned)d[i]);
        }
    }
}

// ======= CSR phase B: per-bucket hist+scan -> rowptr/dinv; LDS-cursor scatter =======
__global__ __launch_bounds__(256) void k_bucketB(
        const uint2* __restrict__ staging, const int* __restrict__ gCursor,
        int* __restrict__ rowptr, float* __restrict__ dinv, int* __restrict__ srcs) {
    __shared__ int sg[256];
    __shared__ int dcnt[256], doff[256], dcur[256];
    int b = blockIdx.x, t = threadIdx.x;
    sg[t] = (t < NB) ? gCursor[t] : 0;
    dcnt[t] = 0;
    __syncthreads();
    int n = sg[b];
    for (int off = 1; off < 256; off <<= 1) {
        int u = (t >= off) ? sg[t - off] : 0;
        __syncthreads();
        sg[t] += u;
        __syncthreads();
    }
    int bb = sg[b] - n;                   // exclusive bucket base
    const uint2* st = staging + (size_t)b * BCAP;
    for (int i = t; i < n; i += 256) atomicAdd(&dcnt[(int)st[i].y & 255], 1);
    __syncthreads();
    doff[t] = dcnt[t];
    __syncthreads();
    for (int off = 1; off < 256; off <<= 1) {
        int u = (t >= off) ? doff[t - off] : 0;
        __syncthreads();
        doff[t] += u;
        __syncthreads();
    }
    int excl = doff[t] - dcnt[t];
    int node = b * 256 + t;
    if (node < N_NODES) {
        rowptr[node] = bb + excl;
        dinv[node] = rsqrtf((float)(dcnt[t] + 1));   // +1 self loop
    }
    dcur[t] = bb + excl;
    if (b == 0 && t == 0) rowptr[N_NODES] = N_EDGES;
    __syncthreads();
    for (int i = t; i < n; i += 256) {
        uint2 r = st[i];
        int p = atomicAdd(&dcur[(int)r.y & 255], 1);
        srcs[p] = (int)r.x;
    }
}

// ================= GCN GEMM (MFMA): h0b = bf16((x @ W) * dinv[row]) =================
__global__ __launch_bounds__(256) void k_gemm_gcn_mfma(
        const float* __restrict__ x, const unsigned short* __restrict__ wfrag,
        const float* __restrict__ dinv, unsigned short* __restrict__ h0b) {
    __shared__ uint4 sA[64 * 32];          // 64 rows x 256 bf16, XOR-swizzled
    int t = threadIdx.x, l = t & 63, w = t >> 6;
    int r0 = blockIdx.x * 64;
    const bf16x8* Wf = ((const bf16x8*)wfrag) + ((w * 64 + l) << 4);
    bf16x8 bfr[8][2];
#pragma unroll
    for (int ks = 0; ks < 8; ++ks) {
        bfr[ks][0] = Wf[ks * 2];
        bfr[ks][1] = Wf[ks * 2 + 1];
    }
    const float4* xg = (const float4*)x;
#pragma unroll
    for (int p = 0; p < 8; ++p) {
        int idx = t + p * 256;
        int row = idx >> 5, c16 = idx & 31;
        int grow = min(r0 + row, N_NODES - 1);
        float4 a0 = xg[(size_t)grow * 64 + c16 * 2];
        float4 a1 = xg[(size_t)grow * 64 + c16 * 2 + 1];
        uint4 o;
        o.x = pack2(a0.x, a0.y); o.y = pack2(a0.z, a0.w);
        o.z = pack2(a1.x, a1.y); o.w = pack2(a1.z, a1.w);
        sA[row * 32 + (c16 ^ (row & 7))] = o;
    }
    __syncthreads();
    f32x4 zero = {0.f, 0.f, 0.f, 0.f};
    f32x4 acc[4][2];
#pragma unroll
    for (int rt = 0; rt < 4; ++rt) { acc[rt][0] = zero; acc[rt][1] = zero; }
    int lr = l & 15, lh = l >> 4;
#pragma unroll
    for (int ks = 0; ks < 8; ++ks) {
        bf16x8 a[4];
#pragma unroll
        for (int rt = 0; rt < 4; ++rt) {
            int row = rt * 16 + lr;
            int c4 = (ks * 4 + lh) ^ (row & 7);
            a[rt] = ((const bf16x8*)sA)[row * 32 + c4];
        }
#pragma unroll
        for (int rt = 0; rt < 4; ++rt) {
            acc[rt][0] = __builtin_amdgcn_mfma_f32_16x16x32_bf16(a[rt], bfr[ks][0], acc[rt][0], 0, 0, 0);
            acc[rt][1] = __builtin_amdgcn_mfma_f32_16x16x32_bf16(a[rt], bfr[ks][1], acc[rt][1], 0, 0, 0);
        }
    }
#pragma unroll
    for (int rt = 0; rt < 4; ++rt)
#pragma unroll
        for (int j = 0; j < 4; ++j) {
            int row = r0 + rt * 16 + lh * 4 + j;
            if (row < N_NODES) {
                float dv = dinv[row];
                size_t base = (size_t)row * H_DIM + w * 32 + lr;
                h0b[base]      = f2bf(acc[rt][0][j] * dv);
                h0b[base + 16] = f2bf(acc[rt][1][j] * dv);
            }
        }
}

// ====== GCN aggregate: bf16 gather, distance-2 load pipeline ======
__global__ void k_gcn_gather(const unsigned short* __restrict__ h0b,
                             const int* __restrict__ rowptr, const int* __restrict__ srcs,
                             const float* __restrict__ dinv, const float* __restrict__ b,
                             unsigned short* __restrict__ hb) {
    int t = threadIdx.x;
    int node = blockIdx.x * 16 + (t >> 4);
    int sl = t & 15;
    if (node >= N_NODES) return;
    uint4 U = ((const uint4*)(h0b + (size_t)node * H_DIM))[sl];   // self loop
    f32x2 acc2[4] = {up2(U.x), up2(U.y), up2(U.z), up2(U.w)};
    int beg = rowptr[node], end = rowptr[node + 1];
    int n = end - beg;
    if (n > 0) {
        const int* sp = srcs + beg;
        int s0 = sp[0];
        int s1 = sp[(n > 1) ? 1 : 0];
        uint4 V0 = ((const uint4*)(h0b + (size_t)s0 * H_DIM))[sl];
        uint4 V1 = ((const uint4*)(h0b + (size_t)s1 * H_DIM))[sl];
        for (int p = 0; p < n; ++p) {
            int pn = (p + 2 < n) ? p + 2 : n - 1;
            int s2 = sp[pn];
            uint4 V2 = ((const uint4*)(h0b + (size_t)s2 * H_DIM))[sl];
            acc2[0] += up2(V0.x); acc2[1] += up2(V0.y);
            acc2[2] += up2(V0.z); acc2[3] += up2(V0.w);
            V0 = V1; V1 = V2;
        }
    }
    float dv = dinv[node];
    float out[8];
#pragma unroll
    for (int i = 0; i < 8; ++i) {
        float a = (i & 1) ? acc2[i >> 1].y : acc2[i >> 1].x;
        float val = a * dv + b[sl * 8 + i];
        out[i] = (val >= 0.f) ? val : LEAKY_SLOPE * val;
    }
    uint4 o;
    o.x = pack2(out[0], out[1]); o.y = pack2(out[2], out[3]);
    o.z = pack2(out[4], out[5]); o.w = pack2(out[6], out[7]);
    ((uint4*)(hb + (size_t)node * H_DIM))[sl] = o;
}

// ==== q'/skip GEMM (MFMA): hb @ [M_mu(128) | Ws_mu | M_ls(128) | Ws_ls], 6 waves ====
__global__ __launch_bounds__(384) void k_qs_mfma(
        const unsigned short* __restrict__ hb, const unsigned short* __restrict__ wfp,
        const float* __restrict__ bpm, const float* __restrict__ bpl,
        const float* __restrict__ bs0, const float* __restrict__ bs1,
        unsigned short* __restrict__ qmb, unsigned short* __restrict__ qlb,
        float* __restrict__ mu_out, float* __restrict__ ls_out) {
    __shared__ uint4 sA[64 * 16];          // 64 rows x 128 bf16, XOR-swizzled
    int t = threadIdx.x, l = t & 63, w = t >> 6;   // w 0..5 (slot)
    int r0 = blockIdx.x * 64;
    const bf16x8* Wf = ((const bf16x8*)wfp) + ((w * 64 + l) << 4);
    bf16x8 bfr[4][4];
#pragma unroll
    for (int ks = 0; ks < 4; ++ks)
#pragma unroll
        for (int ct = 0; ct < 4; ++ct) bfr[ks][ct] = Wf[ks * 4 + ct];
    const uint4* hg = (const uint4*)hb;
#pragma unroll
    for (int p = 0; p < 3; ++p) {
        int idx = t + p * 384;
        if (idx < 1024) {
            int row = idx >> 4, c16 = idx & 15;
            int grow = min(r0 + row, N_NODES - 1);
            sA[row * 16 + (c16 ^ (row & 7))] = hg[(size_t)grow * 16 + c16];
        }
    }
    __syncthreads();
    f32x4 zero = {0.f, 0.f, 0.f, 0.f};
    f32x4 acc[4][4];
#pragma unroll
    for (int rt = 0; rt < 4; ++rt)
#pragma unroll
        for (int ct = 0; ct < 4; ++ct) acc[rt][ct] = zero;
    int lr = l & 15, lh = l >> 4;
#pragma unroll
    for (int ks = 0; ks < 4; ++ks) {
        bf16x8 a[4];
#pragma unroll
        for (int rt = 0; rt < 4; ++rt) {
            int row = rt * 16 + lr;
            int c4 = (ks * 4 + lh) ^ (row & 7);
            a[rt] = ((const bf16x8*)sA)[row * 16 + c4];
        }
#pragma unroll
        for (int rt = 0; rt < 4; ++rt)
#pragma unroll
            for (int ct = 0; ct < 4; ++ct)
                acc[rt][ct] = __builtin_amdgcn_mfma_f32_16x16x32_bf16(a[rt], bfr[ks][ct], acc[rt][ct], 0, 0, 0);
    }
    if (w == 2 || w == 5) {
        const float* bias = (w == 2) ? bs0 : bs1;
        float* op_ = (w == 2) ? mu_out : ls_out;
        float bcol[4];
#pragma unroll
        for (int ct = 0; ct < 4; ++ct) bcol[ct] = bias[ct * 16 + lr];
#pragma unroll
        for (int rt = 0; rt < 4; ++rt)
#pragma unroll
            for (int j = 0; j < 4; ++j) {
                int row = r0 + rt * 16 + lh * 4 + j;
                if (row >= N_NODES) continue;
                float* op = op_ + (size_t)row * D_DIM + lr;
                op[0]  = acc[rt][0][j] + bcol[0];
                op[16] = acc[rt][1][j] + bcol[1];
                op[32] = acc[rt][2][j] + bcol[2];
                op[48] = acc[rt][3][j] + bcol[3];
            }
    } else {
        int conv = (w >= 3);
        int half = conv ? (w - 3) : w;
        const float* bp = conv ? bpl : bpm;
        unsigned short* qb = conv ? qlb : qmb;
        float bcol[4];
#pragma unroll
        for (int ct = 0; ct < 4; ++ct) bcol[ct] = bp[half * 64 + ct * 16 + lr];
#pragma unroll
        for (int rt = 0; rt < 4; ++rt)
#pragma unroll
            for (int j = 0; j < 4; ++j) {
                int row = r0 + rt * 16 + lh * 4 + j;
                if (row >= N_NODES) continue;
                unsigned short* qp = qb + (size_t)row * 128 + half * 64 + lr;
                qp[0]  = f2bf(acc[rt][0][j] + bcol[0]);
                qp[16] = f2bf(acc[rt][1][j] + bcol[1]);
                qp[32] = f2bf(acc[rt][2][j] + bcol[2]);
                qp[48] = f2bf(acc[rt][3][j] + bcol[3]);
            }
    }
}

// ===== attention: h-gather, NO-MAX softmax, distance-1 load pipeline =====
__global__ void k_attn3(const unsigned short* __restrict__ qmb,
                        const unsigned short* __restrict__ qlb,
                        const unsigned short* __restrict__ hb,
                        const int* __restrict__ rowptr, const int* __restrict__ srcs,
                        unsigned short* __restrict__ Sbm, unsigned short* __restrict__ Sbl) {
    int t = threadIdx.x;
    int node = blockIdx.x * 4 + (t >> 6);
    if (node >= N_NODES) return;
    int l = t & 63, g = l >> 4, sl = l & 15;
    uint4 qmu = ((const uint4*)(qmb + (size_t)node * 128))[sl];
    uint4 qlu = ((const uint4*)(qlb + (size_t)node * 128))[sl];
    f32x2 qm2[4] = {up2(qmu.x), up2(qmu.y), up2(qmu.z), up2(qmu.w)};
    f32x2 ql2[4] = {up2(qlu.x), up2(qlu.y), up2(qlu.z), up2(qlu.w)};
    int beg = rowptr[node], end = rowptr[node + 1];
    int deg = end - beg;
    int p0 = beg + ((deg * g) >> 2);
    int p1 = beg + ((deg * (g + 1)) >> 2);
    float den_m = 0.f, den_l = 0.f;
    f32x2 zero2 = {0.f, 0.f};
    f32x2 Sm2[4] = {zero2, zero2, zero2, zero2};
    f32x2 Sl2[4] = {zero2, zero2, zero2, zero2};
    int n = p1 - p0;
    if (n > 0) {
        const int* sp = srcs + p0;
        int s_cur = sp[0];
        uint4 hu = ((const uint4*)(hb + (size_t)s_cur * 128))[sl];
        for (int p = 0; p < n; ++p) {
            int pn = (p + 1 < n) ? p + 1 : n - 1;
            int s_nxt = sp[pn];
            uint4 hun = ((const uint4*)(hb + (size_t)s_nxt * 128))[sl];  // prefetch
            f32x2 h0[4] = {up2(hu.x), up2(hu.y), up2(hu.z), up2(hu.w)};
            f32x2 dm2 = zero2, dl2 = zero2;
#pragma unroll
            for (int i = 0; i < 4; ++i) {
                dm2 += qm2[i] * h0[i];
                dl2 += ql2[i] * h0[i];
            }
            float dmA = red16(dm2.x + dm2.y);
            float dlA = red16(dl2.x + dl2.y);
            float emA = __expf(fminf(dmA, 80.f));
            float elA = __expf(fminf(dlA, 80.f));
            den_m += emA;
            den_l += elA;
            f32x2 em2 = {emA, emA}, el2 = {elA, elA};
#pragma unroll
            for (int i = 0; i < 4; ++i) {
                Sm2[i] += em2 * h0[i];
                Sl2[i] += el2 * h0[i];
            }
            hu = hun;
        }
    }
    // merge 4 group states per conv: plain sums (no max to reconcile)
    den_m += __shfl_xor(den_m, 16); den_m += __shfl_xor(den_m, 32);
    den_l += __shfl_xor(den_l, 16); den_l += __shfl_xor(den_l, 32);
#pragma unroll
    for (int i = 0; i < 4; ++i) {
        Sm2[i].x += __shfl_xor(Sm2[i].x, 16); Sm2[i].x += __shfl_xor(Sm2[i].x, 32);
        Sm2[i].y += __shfl_xor(Sm2[i].y, 16); Sm2[i].y += __shfl_xor(Sm2[i].y, 32);
        Sl2[i].x += __shfl_xor(Sl2[i].x, 16); Sl2[i].x += __shfl_xor(Sl2[i].x, 32);
        Sl2[i].y += __shfl_xor(Sl2[i].y, 16); Sl2[i].y += __shfl_xor(Sl2[i].y, 32);
    }
    if (g == 0) {
        float inv = 1.f / (den_m + 1e-16f);
        uint4 o;
        o.x = pack2(Sm2[0].x * inv, Sm2[0].y * inv);
        o.y = pack2(Sm2[1].x * inv, Sm2[1].y * inv);
        o.z = pack2(Sm2[2].x * inv, Sm2[2].y * inv);
        o.w = pack2(Sm2[3].x * inv, Sm2[3].y * inv);
        ((uint4*)Sbm)[(size_t)node * 16 + sl] = o;
        float invl = 1.f / (den_l + 1e-16f);
        uint4 ol;
        ol.x = pack2(Sl2[0].x * invl, Sl2[0].y * invl);
        ol.y = pack2(Sl2[1].x * invl, Sl2[1].y * invl);
        ol.z = pack2(Sl2[2].x * invl, Sl2[2].y * invl);
        ol.w = pack2(Sl2[3].x * invl, Sl2[3].y * invl);
        ((uint4*)Sbl)[(size_t)node * 16 + sl] = ol;
    }
}

// ===== proj: out += Sb @ Wv + bv*[deg>0]; clamp ls. 4 waves: conv=w&1, rowhalf=w>>1 =====
__global__ __launch_bounds__(256) void k_proj(
        const unsigned short* __restrict__ Sbm, const unsigned short* __restrict__ Sbl,
        const unsigned short* __restrict__ wfv,
        const float* __restrict__ bv0, const float* __restrict__ bv1,
        const int* __restrict__ rowptr,
        float* __restrict__ mu_out, float* __restrict__ ls_out) {
    __shared__ uint4 sA[2 * 64 * 16];
    int t = threadIdx.x, l = t & 63, w = t >> 6;
    int conv = w & 1, rh = w >> 1;
    int r0 = blockIdx.x * 64;
    const bf16x8* Wf = ((const bf16x8*)wfv) + ((conv * 64 + l) << 4);
    bf16x8 bfr[4][4];
#pragma unroll
    for (int ks = 0; ks < 4; ++ks)
#pragma unroll
        for (int ct = 0; ct < 4; ++ct) bfr[ks][ct] = Wf[ks * 4 + ct];
#pragma unroll
    for (int p = 0; p < 8; ++p) {
        int idx = t + p * 256;             // 0..2047
        int buf = idx >> 10, rem = idx & 1023;
        int row = rem >> 4, c16 = rem & 15;
        int grow = min(r0 + row, N_NODES - 1);
        const uint4* srcp = (const uint4*)(buf ? Sbl : Sbm);
        sA[buf * 1024 + row * 16 + (c16 ^ (row & 7))] = srcp[(size_t)grow * 16 + c16];
    }
    __syncthreads();
    f32x4 zero = {0.f, 0.f, 0.f, 0.f};
    f32x4 acc[2][4];
#pragma unroll
    for (int rt = 0; rt < 2; ++rt)
#pragma unroll
        for (int ct = 0; ct < 4; ++ct) acc[rt][ct] = zero;
    int lr = l & 15, lh = l >> 4;
#pragma unroll
    for (int ks = 0; ks < 4; ++ks) {
        bf16x8 a[2];
#pragma unroll
        for (int rt = 0; rt < 2; ++rt) {
            int row = rh * 32 + rt * 16 + lr;
            int c4 = (ks * 4 + lh) ^ (row & 7);
            a[rt] = ((const bf16x8*)sA)[conv * 1024 + row * 16 + c4];
        }
#pragma unroll
        for (int rt = 0; rt < 2; ++rt)
#pragma unroll
            for (int ct = 0; ct < 4; ++ct)
                acc[rt][ct] = __builtin_amdgcn_mfma_f32_16x16x32_bf16(a[rt], bfr[ks][ct], acc[rt][ct], 0, 0, 0);
    }
    const float* bv = conv ? bv1 : bv0;
    float* ob = conv ? ls_out : mu_out;
    float bcol[4];
#pragma unroll
    for (int ct = 0; ct < 4; ++ct) bcol[ct] = bv[ct * 16 + lr];
#pragma unroll
    for (int rt = 0; rt < 2; ++rt)
#pragma unroll
        for (int j = 0; j < 4; ++j) {
            int row = r0 + rh * 32 + rt * 16 + lh * 4 + j;
            if (row >= N_NODES) continue;
            float wsum = (rowptr[row + 1] > rowptr[row]) ? 1.f : 0.f;
            float* op = ob + (size_t)row * D_DIM + lr;
            float v0 = acc[rt][0][j] + bcol[0] * wsum + op[0];
            float v1 = acc[rt][1][j] + bcol[1] * wsum + op[16];
            float v2 = acc[rt][2][j] + bcol[2] * wsum + op[32];
            float v3 = acc[rt][3][j] + bcol[3] * wsum + op[48];
            if (conv) {
                v0 = fminf(v0, MAX_LOGSTD); v1 = fminf(v1, MAX_LOGSTD);
                v2 = fminf(v2, MAX_LOGSTD); v3 = fminf(v3, MAX_LOGSTD);
            }
            op[0] = v0; op[16] = v1; op[32] = v2; op[48] = v3;
        }
}

// ================= launch =================
extern "C" void kernel_launch(void* const* d_in, const int* in_sizes, int n_in,
                              void* d_out, int out_size, void* d_ws, size_t ws_size,
                              hipStream_t stream) {
    const float* x     = (const float*)d_in[0];
    const int*   ei    = (const int*)d_in[1];
    const int*   src   = ei;
    const int*   dst   = ei + N_EDGES;
    const float* W_gcn = (const float*)d_in[2];
    const float* b_gcn = (const float*)d_in[3];
    const float* Wm[8]; const float* Wl8[8];
    for (int i = 0; i < 8; ++i) { Wm[i] = (const float*)d_in[4 + i]; Wl8[i] = (const float*)d_in[12 + i]; }

    float* out    = (float*)d_out;
    float* mu_out = out;
    float* ls_out = out + N_NODES * D_DIM;

    float* ws   = (float*)d_ws;
    float* dinv = ws;                                          // N
    float* Mf   = dinv + N_NODES;                              // 2*128*128
    float* bpm  = Mf + 32768;                                  // 128
    float* bpl  = bpm + 128;                                   // 128
    unsigned short* hb  = (unsigned short*)(bpl + 128);        // N*128 bf16
    unsigned short* h0b = hb + (size_t)N_NODES * H_DIM;        // N*128 (-> Sbm)
    unsigned short* qmb = h0b + (size_t)N_NODES * H_DIM;       // N*128 (staging aliases)
    unsigned short* qlb = qmb + (size_t)N_NODES * H_DIM;       // N*128
    unsigned short* Sbl = qlb + (size_t)N_NODES * H_DIM;       // N*128
    unsigned short* wfg = Sbl + (size_t)N_NODES * H_DIM;       // 32768
    unsigned short* wfp = wfg + 32768;                         // 49152
    unsigned short* wfv = wfp + 49152;                         // 16384
    int* rowptr  = (int*)(wfv + 16384);           // N+4
    int* srcs    = rowptr + N_NODES + 4;          // E
    int* gCursor = srcs + N_EDGES;                // 256
    uint2* staging = (uint2*)qmb;                 // 7.84 MB, dead before k_qs
    unsigned short* Sbm = h0b;                    // h0b dead after gather

    const int B = 256;
    k_prepM<<<129, B, 0, stream>>>(Wm[0], Wm[2], Wm[1], Wl8[0], Wl8[2], Wl8[1],
                                   Mf, bpm, bpl);
    k_prep<<<385, B, 0, stream>>>(W_gcn, Mf, Wm[6], Wl8[6], Wm[4], Wl8[4],
                                  wfg, wfp, wfv, gCursor);
    k_bucketA<<<(N_EDGES + 4095) / 4096, B, 0, stream>>>(src, dst, gCursor, staging);
    k_bucketB<<<NB, B, 0, stream>>>(staging, gCursor, rowptr, dinv, srcs);

    // GCN
    k_gemm_gcn_mfma<<<GEMM_BLK, B, 0, stream>>>(x, wfg, dinv, h0b);
    k_gcn_gather<<<(N_NODES + 15) / 16, B, 0, stream>>>(h0b, rowptr, srcs, dinv, b_gcn, hb);

    // q' + skip GEMM (both convs), then h-gather attention, then Wv projection
    k_qs_mfma<<<GEMM_BLK, 384, 0, stream>>>(hb, wfp, bpm, bpl, Wm[7], Wl8[7],
                                            qmb, qlb, mu_out, ls_out);
    k_attn3<<<(N_NODES + 3) / 4, B, 0, stream>>>(qmb, qlb, hb, rowptr, srcs, Sbm, Sbl);
    k_proj<<<GEMM_BLK, B, 0, stream>>>(Sbm, Sbl, wfv, Wm[5], Wl8[5], rowptr,
                                       mu_out, ls_out);
}

// Round 16
// 194.422 us; speedup vs baseline: 1.0439x; 1.0439x over previous
//
#include <hip/hip_runtime.h>
#include <math.h>

#define N_NODES 50000
#define N_EDGES 800000
#define F_IN    256
#define H_DIM   128
#define D_DIM   64
#define MAX_LOGSTD 10.0f
#define LEAKY_SLOPE 0.01f

#define NB       196            // dst buckets (dst>>8)
#define BCAP     5000           // per-bucket staging capacity (mean 4082, +14 sigma)
#define GEMM_BLK 782            // ceil(N_NODES/64)

using bf16x8 = __attribute__((ext_vector_type(8))) short;
using f32x4  = __attribute__((ext_vector_type(4))) float;
using f32x2  = __attribute__((ext_vector_type(2))) float;

// ---------- bf16 helpers (RNE pack, shift unpack) ----------
__device__ inline float bflo(unsigned u) { return __uint_as_float(u << 16); }
__device__ inline float bfhi(unsigned u) { return __uint_as_float(u & 0xFFFF0000u); }
__device__ inline unsigned short f2bf(float f) {
    unsigned u = __float_as_uint(f);
    u += 0x7FFFu + ((u >> 16) & 1u);
    return (unsigned short)(u >> 16);
}
__device__ inline unsigned pack2(float a, float b) {
    return (unsigned)f2bf(a) | ((unsigned)f2bf(b) << 16);
}
__device__ inline f32x2 up2(unsigned u) {
    f32x2 r;
    r.x = __uint_as_float(u << 16);
    r.y = __uint_as_float(u & 0xFFFF0000u);
    return r;
}
__device__ inline float red16(float d) {
    d += __shfl_xor(d, 1); d += __shfl_xor(d, 2);
    d += __shfl_xor(d, 4); d += __shfl_xor(d, 8);
    return d;
}

// ======= prepM: M = Wq@Wk^T/8 (128x128 per conv), b' = bq@Wk^T/8 =======
__global__ void k_prepM(const float* __restrict__ Wq0, const float* __restrict__ Wk0,
                        const float* __restrict__ bq0,
                        const float* __restrict__ Wq1, const float* __restrict__ Wk1,
                        const float* __restrict__ bq1,
                        float* __restrict__ Mf, float* __restrict__ bpm,
                        float* __restrict__ bpl) {
    int blk = blockIdx.x, t = threadIdx.x;
    if (blk < 128) {
        int tid = blk * 256 + t;          // 0..32767
        int conv = tid >> 14;
        int rem = tid & 16383;
        int i = rem >> 7, jj = rem & 127;
        const float* Wq = conv ? Wq1 : Wq0;
        const float* Wk = conv ? Wk1 : Wk0;
        float s = 0.f;
#pragma unroll 8
        for (int n = 0; n < 64; ++n) s = fmaf(Wq[i * 64 + n], Wk[jj * 64 + n], s);
        Mf[conv * 16384 + i * 128 + jj] = s * 0.125f;
    } else {
        int jj = t & 127;
        int conv = t >> 7;
        const float* Wk = conv ? Wk1 : Wk0;
        const float* bq = conv ? bq1 : bq0;
        float s = 0.f;
#pragma unroll 8
        for (int n = 0; n < 64; ++n) s = fmaf(bq[n], Wk[jj * 64 + n], s);
        if (conv) bpl[jj] = s * 0.125f; else bpm[jj] = s * 0.125f;
    }
}

// ======= prep: weight fragment shuffles (wfg, wfp 6 slots, wfv 2 slots) + init =======
__global__ void k_prep(const float* __restrict__ Wg, const float* __restrict__ Mf,
                       const float* __restrict__ Ws0, const float* __restrict__ Ws1,
                       const float* __restrict__ Wv0, const float* __restrict__ Wv1,
                       unsigned short* __restrict__ wfg, unsigned short* __restrict__ wfp,
                       unsigned short* __restrict__ wfv, int* __restrict__ gCursor) {
    int blk = blockIdx.x, t = threadIdx.x;
    if (blk == 384) { if (t < 256) gCursor[t] = 0; return; }
    if (blk < 128) {
        int tid = blk * 256 + t;
        int j = tid & 7, ct = (tid >> 3) & 1, ks = (tid >> 4) & 7;
        int l = (tid >> 7) & 63, w = tid >> 13;
        int k = ks * 32 + (l >> 4) * 8 + j;
        int n = w * 32 + ct * 16 + (l & 15);
        wfg[tid] = f2bf(Wg[k * H_DIM + n]);
    } else if (blk < 320) {
        // wfp: slots 0,1: M_mu halves; 2: Ws_mu; 3,4: M_ls halves; 5: Ws_ls. K=128.
        int tid = (blk - 128) * 256 + t;   // 0..49151
        int j = tid & 7, ct = (tid >> 3) & 3, ks = (tid >> 5) & 3;
        int l = (tid >> 7) & 63, w = tid >> 13;
        int k = ks * 32 + (l >> 4) * 8 + j;
        int n = ct * 16 + (l & 15);
        float val;
        if (w == 2)      val = Ws0[k * D_DIM + n];
        else if (w == 5) val = Ws1[k * D_DIM + n];
        else {
            int conv = (w >= 3);
            int half = conv ? (w - 3) : w;
            val = Mf[conv * 16384 + k * 128 + half * 64 + n];
        }
        wfp[tid] = f2bf(val);
    } else {
        // wfv: slot 0: Wv_mu, slot 1: Wv_ls (128x64)
        int tid = (blk - 320) * 256 + t;   // 0..16383
        int j = tid & 7, ct = (tid >> 3) & 3, ks = (tid >> 5) & 3;
        int l = (tid >> 7) & 63, w = tid >> 13;
        int k = ks * 32 + (l >> 4) * 8 + j;
        int n = ct * 16 + (l & 15);
        const float* Wv = w ? Wv1 : Wv0;
        wfv[tid] = f2bf(Wv[k * D_DIM + n]);
    }
}

// ======= CSR phase A: bucket edges into contiguous staging chunks =======
__global__ __launch_bounds__(256) void k_bucketA(
        const int* __restrict__ src, const int* __restrict__ dst,
        int* __restrict__ gCursor, uint2* __restrict__ staging) {
    __shared__ int cnt[NB];
    __shared__ int base[NB];
    int t = threadIdx.x;
    int e0 = blockIdx.x * 4096;
    for (int i = t; i < NB; i += 256) cnt[i] = 0;
    __syncthreads();
    int s[16], d[16], b[16];
#pragma unroll
    for (int i = 0; i < 16; ++i) {
        int e = e0 + t + i * 256;
        if (e < N_EDGES) {
            s[i] = src[e]; d[i] = dst[e]; b[i] = d[i] >> 8;
            atomicAdd(&cnt[b[i]], 1);
        } else b[i] = -1;
    }
    __syncthreads();
    for (int i = t; i < NB; i += 256) base[i] = atomicAdd(&gCursor[i], cnt[i]);
    __syncthreads();
    for (int i = t; i < NB; i += 256) cnt[i] = 0;
    __syncthreads();
#pragma unroll
    for (int i = 0; i < 16; ++i) {
        if (b[i] >= 0) {
            int lp = atomicAdd(&cnt[b[i]], 1);
            staging[(size_t)b[i] * BCAP + base[b[i]] + lp] =
                make_uint2((unsigned)s[i], (unsigned)d[i]);
        }
    }
}

// ======= CSR phase B: per-bucket hist+scan -> rowptr/dinv; LDS-cursor scatter =======
__global__ __launch_bounds__(256) void k_bucketB(
        const uint2* __restrict__ staging, const int* __restrict__ gCursor,
        int* __restrict__ rowptr, float* __restrict__ dinv, int* __restrict__ srcs) {
    __shared__ int sg[256];
    __shared__ int dcnt[256], doff[256], dcur[256];
    int b = blockIdx.x, t = threadIdx.x;
    sg[t] = (t < NB) ? gCursor[t] : 0;
    dcnt[t] = 0;
    __syncthreads();
    int n = sg[b];
    for (int off = 1; off < 256; off <<= 1) {
        int u = (t >= off) ? sg[t - off] : 0;
        __syncthreads();
        sg[t] += u;
        __syncthreads();
    }
    int bb = sg[b] - n;                   // exclusive bucket base
    const uint2* st = staging + (size_t)b * BCAP;
    for (int i = t; i < n; i += 256) atomicAdd(&dcnt[(int)st[i].y & 255], 1);
    __syncthreads();
    doff[t] = dcnt[t];
    __syncthreads();
    for (int off = 1; off < 256; off <<= 1) {
        int u = (t >= off) ? doff[t - off] : 0;
        __syncthreads();
        doff[t] += u;
        __syncthreads();
    }
    int excl = doff[t] - dcnt[t];
    int node = b * 256 + t;
    if (node < N_NODES) {
        rowptr[node] = bb + excl;
        dinv[node] = rsqrtf((float)(dcnt[t] + 1));   // +1 self loop
    }
    dcur[t] = bb + excl;
    if (b == 0 && t == 0) rowptr[N_NODES] = N_EDGES;
    __syncthreads();
    for (int i = t; i < n; i += 256) {
        uint2 r = st[i];
        int p = atomicAdd(&dcur[(int)r.y & 255], 1);
        srcs[p] = (int)r.x;
    }
}

// ================= GCN GEMM (MFMA): h0b = bf16((x @ W) * dinv[row]) =================
__global__ __launch_bounds__(256) void k_gemm_gcn_mfma(
        const float* __restrict__ x, const unsigned short* __restrict__ wfrag,
        const float* __restrict__ dinv, unsigned short* __restrict__ h0b) {
    __shared__ uint4 sA[64 * 32];          // 64 rows x 256 bf16, XOR-swizzled
    int t = threadIdx.x, l = t & 63, w = t >> 6;
    int r0 = blockIdx.x * 64;
    const bf16x8* Wf = ((const bf16x8*)wfrag) + ((w * 64 + l) << 4);
    bf16x8 bfr[8][2];
#pragma unroll
    for (int ks = 0; ks < 8; ++ks) {
        bfr[ks][0] = Wf[ks * 2];
        bfr[ks][1] = Wf[ks * 2 + 1];
    }
    const float4* xg = (const float4*)x;
#pragma unroll
    for (int p = 0; p < 8; ++p) {
        int idx = t + p * 256;
        int row = idx >> 5, c16 = idx & 31;
        int grow = min(r0 + row, N_NODES - 1);
        float4 a0 = xg[(size_t)grow * 64 + c16 * 2];
        float4 a1 = xg[(size_t)grow * 64 + c16 * 2 + 1];
        uint4 o;
        o.x = pack2(a0.x, a0.y); o.y = pack2(a0.z, a0.w);
        o.z = pack2(a1.x, a1.y); o.w = pack2(a1.z, a1.w);
        sA[row * 32 + (c16 ^ (row & 7))] = o;
    }
    __syncthreads();
    f32x4 zero = {0.f, 0.f, 0.f, 0.f};
    f32x4 acc[4][2];
#pragma unroll
    for (int rt = 0; rt < 4; ++rt) { acc[rt][0] = zero; acc[rt][1] = zero; }
    int lr = l & 15, lh = l >> 4;
#pragma unroll
    for (int ks = 0; ks < 8; ++ks) {
        bf16x8 a[4];
#pragma unroll
        for (int rt = 0; rt < 4; ++rt) {
            int row = rt * 16 + lr;
            int c4 = (ks * 4 + lh) ^ (row & 7);
            a[rt] = ((const bf16x8*)sA)[row * 32 + c4];
        }
#pragma unroll
        for (int rt = 0; rt < 4; ++rt) {
            acc[rt][0] = __builtin_amdgcn_mfma_f32_16x16x32_bf16(a[rt], bfr[ks][0], acc[rt][0], 0, 0, 0);
            acc[rt][1] = __builtin_amdgcn_mfma_f32_16x16x32_bf16(a[rt], bfr[ks][1], acc[rt][1], 0, 0, 0);
        }
    }
#pragma unroll
    for (int rt = 0; rt < 4; ++rt)
#pragma unroll
        for (int j = 0; j < 4; ++j) {
            int row = r0 + rt * 16 + lh * 4 + j;
            if (row < N_NODES) {
                float dv = dinv[row];
                size_t base = (size_t)row * H_DIM + w * 32 + lr;
                h0b[base]      = f2bf(acc[rt][0][j] * dv);
                h0b[base + 16] = f2bf(acc[rt][1][j] * dv);
            }
        }
}

// ====== GCN aggregate: bf16 gather, float2 packed accumulate, 2-edge unroll ======
__global__ void k_gcn_gather(const unsigned short* __restrict__ h0b,
                             const int* __restrict__ rowptr, const int* __restrict__ srcs,
                             const float* __restrict__ dinv, const float* __restrict__ b,
                             unsigned short* __restrict__ hb) {
    int t = threadIdx.x;
    int node = blockIdx.x * 16 + (t >> 4);
    int sl = t & 15;
    if (node >= N_NODES) return;
    uint4 U = ((const uint4*)(h0b + (size_t)node * H_DIM))[sl];   // self loop
    f32x2 acc2[4] = {up2(U.x), up2(U.y), up2(U.z), up2(U.w)};
    int beg = rowptr[node], end = rowptr[node + 1];
    int p = beg;
    for (; p + 1 < end; p += 2) {
        int s0 = srcs[p], s1 = srcs[p + 1];
        uint4 V0 = ((const uint4*)(h0b + (size_t)s0 * H_DIM))[sl];
        uint4 V1 = ((const uint4*)(h0b + (size_t)s1 * H_DIM))[sl];
        acc2[0] += up2(V0.x); acc2[1] += up2(V0.y);
        acc2[2] += up2(V0.z); acc2[3] += up2(V0.w);
        acc2[0] += up2(V1.x); acc2[1] += up2(V1.y);
        acc2[2] += up2(V1.z); acc2[3] += up2(V1.w);
    }
    if (p < end) {
        int s = srcs[p];
        uint4 V = ((const uint4*)(h0b + (size_t)s * H_DIM))[sl];
        acc2[0] += up2(V.x); acc2[1] += up2(V.y);
        acc2[2] += up2(V.z); acc2[3] += up2(V.w);
    }
    float dv = dinv[node];
    float out[8];
#pragma unroll
    for (int i = 0; i < 8; ++i) {
        float a = (i & 1) ? acc2[i >> 1].y : acc2[i >> 1].x;
        float val = a * dv + b[sl * 8 + i];
        out[i] = (val >= 0.f) ? val : LEAKY_SLOPE * val;
    }
    uint4 o;
    o.x = pack2(out[0], out[1]); o.y = pack2(out[2], out[3]);
    o.z = pack2(out[4], out[5]); o.w = pack2(out[6], out[7]);
    ((uint4*)(hb + (size_t)node * H_DIM))[sl] = o;
}

// ==== q'/skip GEMM (MFMA): hb @ [M_mu(128) | Ws_mu | M_ls(128) | Ws_ls], 6 waves ====
__global__ __launch_bounds__(384) void k_qs_mfma(
        const unsigned short* __restrict__ hb, const unsigned short* __restrict__ wfp,
        const float* __restrict__ bpm, const float* __restrict__ bpl,
        const float* __restrict__ bs0, const float* __restrict__ bs1,
        unsigned short* __restrict__ qmb, unsigned short* __restrict__ qlb,
        float* __restrict__ mu_out, float* __restrict__ ls_out) {
    __shared__ uint4 sA[64 * 16];          // 64 rows x 128 bf16, XOR-swizzled
    int t = threadIdx.x, l = t & 63, w = t >> 6;   // w 0..5 (slot)
    int r0 = blockIdx.x * 64;
    const bf16x8* Wf = ((const bf16x8*)wfp) + ((w * 64 + l) << 4);
    bf16x8 bfr[4][4];
#pragma unroll
    for (int ks = 0; ks < 4; ++ks)
#pragma unroll
        for (int ct = 0; ct < 4; ++ct) bfr[ks][ct] = Wf[ks * 4 + ct];
    const uint4* hg = (const uint4*)hb;
#pragma unroll
    for (int p = 0; p < 3; ++p) {
        int idx = t + p * 384;
        if (idx < 1024) {
            int row = idx >> 4, c16 = idx & 15;
            int grow = min(r0 + row, N_NODES - 1);
            sA[row * 16 + (c16 ^ (row & 7))] = hg[(size_t)grow * 16 + c16];
        }
    }
    __syncthreads();
    f32x4 zero = {0.f, 0.f, 0.f, 0.f};
    f32x4 acc[4][4];
#pragma unroll
    for (int rt = 0; rt < 4; ++rt)
#pragma unroll
        for (int ct = 0; ct < 4; ++ct) acc[rt][ct] = zero;
    int lr = l & 15, lh = l >> 4;
#pragma unroll
    for (int ks = 0; ks < 4; ++ks) {
        bf16x8 a[4];
#pragma unroll
        for (int rt = 0; rt < 4; ++rt) {
            int row = rt * 16 + lr;
            int c4 = (ks * 4 + lh) ^ (row & 7);
            a[rt] = ((const bf16x8*)sA)[row * 16 + c4];
        }
#pragma unroll
        for (int rt = 0; rt < 4; ++rt)
#pragma unroll
            for (int ct = 0; ct < 4; ++ct)
                acc[rt][ct] = __builtin_amdgcn_mfma_f32_16x16x32_bf16(a[rt], bfr[ks][ct], acc[rt][ct], 0, 0, 0);
    }
    if (w == 2 || w == 5) {
        const float* bias = (w == 2) ? bs0 : bs1;
        float* op_ = (w == 2) ? mu_out : ls_out;
        float bcol[4];
#pragma unroll
        for (int ct = 0; ct < 4; ++ct) bcol[ct] = bias[ct * 16 + lr];
#pragma unroll
        for (int rt = 0; rt < 4; ++rt)
#pragma unroll
            for (int j = 0; j < 4; ++j) {
                int row = r0 + rt * 16 + lh * 4 + j;
                if (row >= N_NODES) continue;
                float* op = op_ + (size_t)row * D_DIM + lr;
                op[0]  = acc[rt][0][j] + bcol[0];
                op[16] = acc[rt][1][j] + bcol[1];
                op[32] = acc[rt][2][j] + bcol[2];
                op[48] = acc[rt][3][j] + bcol[3];
            }
    } else {
        int conv = (w >= 3);
        int half = conv ? (w - 3) : w;
        const float* bp = conv ? bpl : bpm;
        unsigned short* qb = conv ? qlb : qmb;
        float bcol[4];
#pragma unroll
        for (int ct = 0; ct < 4; ++ct) bcol[ct] = bp[half * 64 + ct * 16 + lr];
#pragma unroll
        for (int rt = 0; rt < 4; ++rt)
#pragma unroll
            for (int j = 0; j < 4; ++j) {
                int row = r0 + rt * 16 + lh * 4 + j;
                if (row >= N_NODES) continue;
                unsigned short* qp = qb + (size_t)row * 128 + half * 64 + lr;
                qp[0]  = f2bf(acc[rt][0][j] + bcol[0]);
                qp[16] = f2bf(acc[rt][1][j] + bcol[1]);
                qp[32] = f2bf(acc[rt][2][j] + bcol[2]);
                qp[48] = f2bf(acc[rt][3][j] + bcol[3]);
            }
    }
}

// ===== attention: h-gather, NO-MAX softmax, float2 packed math, single-edge loop =====
__global__ void k_attn3(const unsigned short* __restrict__ qmb,
                        const unsigned short* __restrict__ qlb,
                        const unsigned short* __restrict__ hb,
                        const int* __restrict__ rowptr, const int* __restrict__ srcs,
                        unsigned short* __restrict__ Sbm, unsigned short* __restrict__ Sbl) {
    int t = threadIdx.x;
    int node = blockIdx.x * 4 + (t >> 6);
    if (node >= N_NODES) return;
    int l = t & 63, g = l >> 4, sl = l & 15;
    uint4 qmu = ((const uint4*)(qmb + (size_t)node * 128))[sl];
    uint4 qlu = ((const uint4*)(qlb + (size_t)node * 128))[sl];
    f32x2 qm2[4] = {up2(qmu.x), up2(qmu.y), up2(qmu.z), up2(qmu.w)};
    f32x2 ql2[4] = {up2(qlu.x), up2(qlu.y), up2(qlu.z), up2(qlu.w)};
    int beg = rowptr[node], end = rowptr[node + 1];
    int deg = end - beg;
    int p0 = beg + ((deg * g) >> 2);
    int p1 = beg + ((deg * (g + 1)) >> 2);
    float den_m = 0.f, den_l = 0.f;
    f32x2 zero2 = {0.f, 0.f};
    f32x2 Sm2[4] = {zero2, zero2, zero2, zero2};
    f32x2 Sl2[4] = {zero2, zero2, zero2, zero2};
    for (int p = p0; p < p1; ++p) {
        int s = srcs[p];
        uint4 hu = ((const uint4*)(hb + (size_t)s * 128))[sl];
        f32x2 h0[4] = {up2(hu.x), up2(hu.y), up2(hu.z), up2(hu.w)};
        f32x2 dm2 = zero2, dl2 = zero2;
#pragma unroll
        for (int i = 0; i < 4; ++i) {
            dm2 += qm2[i] * h0[i];
            dl2 += ql2[i] * h0[i];
        }
        float dmA = red16(dm2.x + dm2.y);
        float dlA = red16(dl2.x + dl2.y);
        float emA = __expf(fminf(dmA, 80.f));
        float elA = __expf(fminf(dlA, 80.f));
        den_m += emA;
        den_l += elA;
        f32x2 em2 = {emA, emA}, el2 = {elA, elA};
#pragma unroll
        for (int i = 0; i < 4; ++i) {
            Sm2[i] += em2 * h0[i];
            Sl2[i] += el2 * h0[i];
        }
    }
    // merge 4 group states per conv: plain sums (no max to reconcile)
    den_m += __shfl_xor(den_m, 16); den_m += __shfl_xor(den_m, 32);
    den_l += __shfl_xor(den_l, 16); den_l += __shfl_xor(den_l, 32);
#pragma unroll
    for (int i = 0; i < 4; ++i) {
        Sm2[i].x += __shfl_xor(Sm2[i].x, 16); Sm2[i].x += __shfl_xor(Sm2[i].x, 32);
        Sm2[i].y += __shfl_xor(Sm2[i].y, 16); Sm2[i].y += __shfl_xor(Sm2[i].y, 32);
        Sl2[i].x += __shfl_xor(Sl2[i].x, 16); Sl2[i].x += __shfl_xor(Sl2[i].x, 32);
        Sl2[i].y += __shfl_xor(Sl2[i].y, 16); Sl2[i].y += __shfl_xor(Sl2[i].y, 32);
    }
    if (g == 0) {
        float inv = 1.f / (den_m + 1e-16f);
        uint4 o;
        o.x = pack2(Sm2[0].x * inv, Sm2[0].y * inv);
        o.y = pack2(Sm2[1].x * inv, Sm2[1].y * inv);
        o.z = pack2(Sm2[2].x * inv, Sm2[2].y * inv);
        o.w = pack2(Sm2[3].x * inv, Sm2[3].y * inv);
        ((uint4*)Sbm)[(size_t)node * 16 + sl] = o;
        float invl = 1.f / (den_l + 1e-16f);
        uint4 ol;
        ol.x = pack2(Sl2[0].x * invl, Sl2[0].y * invl);
        ol.y = pack2(Sl2[1].x * invl, Sl2[1].y * invl);
        ol.z = pack2(Sl2[2].x * invl, Sl2[2].y * invl);
        ol.w = pack2(Sl2[3].x * invl, Sl2[3].y * invl);
        ((uint4*)Sbl)[(size_t)node * 16 + sl] = ol;
    }
}

// ===== proj: out += Sb @ Wv + bv*[deg>0]; clamp ls. 4 waves: conv=w&1, rowhalf=w>>1 =====
__global__ __launch_bounds__(256) void k_proj(
        const unsigned short* __restrict__ Sbm, const unsigned short* __restrict__ Sbl,
        const unsigned short* __restrict__ wfv,
        const float* __restrict__ bv0, const float* __restrict__ bv1,
        const int* __restrict__ rowptr,
        float* __restrict__ mu_out, float* __restrict__ ls_out) {
    __shared__ uint4 sA[2 * 64 * 16];
    int t = threadIdx.x, l = t & 63, w = t >> 6;
    int conv = w & 1, rh = w >> 1;
    int r0 = blockIdx.x * 64;
    const bf16x8* Wf = ((const bf16x8*)wfv) + ((conv * 64 + l) << 4);
    bf16x8 bfr[4][4];
#pragma unroll
    for (int ks = 0; ks < 4; ++ks)
#pragma unroll
        for (int ct = 0; ct < 4; ++ct) bfr[ks][ct] = Wf[ks * 4 + ct];
#pragma unroll
    for (int p = 0; p < 8; ++p) {
        int idx = t + p * 256;             // 0..2047
        int buf = idx >> 10, rem = idx & 1023;
        int row = rem >> 4, c16 = rem & 15;
        int grow = min(r0 + row, N_NODES - 1);
        const uint4* srcp = (const uint4*)(buf ? Sbl : Sbm);
        sA[buf * 1024 + row * 16 + (c16 ^ (row & 7))] = srcp[(size_t)grow * 16 + c16];
    }
    __syncthreads();
    f32x4 zero = {0.f, 0.f, 0.f, 0.f};
    f32x4 acc[2][4];
#pragma unroll
    for (int rt = 0; rt < 2; ++rt)
#pragma unroll
        for (int ct = 0; ct < 4; ++ct) acc[rt][ct] = zero;
    int lr = l & 15, lh = l >> 4;
#pragma unroll
    for (int ks = 0; ks < 4; ++ks) {
        bf16x8 a[2];
#pragma unroll
        for (int rt = 0; rt < 2; ++rt) {
            int row = rh * 32 + rt * 16 + lr;
            int c4 = (ks * 4 + lh) ^ (row & 7);
            a[rt] = ((const bf16x8*)sA)[conv * 1024 + row * 16 + c4];
        }
#pragma unroll
        for (int rt = 0; rt < 2; ++rt)
#pragma unroll
            for (int ct = 0; ct < 4; ++ct)
                acc[rt][ct] = __builtin_amdgcn_mfma_f32_16x16x32_bf16(a[rt], bfr[ks][ct], acc[rt][ct], 0, 0, 0);
    }
    const float* bv = conv ? bv1 : bv0;
    float* ob = conv ? ls_out : mu_out;
    float bcol[4];
#pragma unroll
    for (int ct = 0; ct < 4; ++ct) bcol[ct] = bv[ct * 16 + lr];
#pragma unroll
    for (int rt = 0; rt < 2; ++rt)
#pragma unroll
        for (int j = 0; j < 4; ++j) {
            int row = r0 + rh * 32 + rt * 16 + lh * 4 + j;
            if (row >= N_NODES) continue;
            float wsum = (rowptr[row + 1] > rowptr[row]) ? 1.f : 0.f;
            float* op = ob + (size_t)row * D_DIM + lr;
            float v0 = acc[rt][0][j] + bcol[0] * wsum + op[0];
            float v1 = acc[rt][1][j] + bcol[1] * wsum + op[16];
            float v2 = acc[rt][2][j] + bcol[2] * wsum + op[32];
            float v3 = acc[rt][3][j] + bcol[3] * wsum + op[48];
            if (conv) {
                v0 = fminf(v0, MAX_LOGSTD); v1 = fminf(v1, MAX_LOGSTD);
                v2 = fminf(v2, MAX_LOGSTD); v3 = fminf(v3, MAX_LOGSTD);
            }
            op[0] = v0; op[16] = v1; op[32] = v2; op[48] = v3;
        }
}

// ================= launch =================
extern "C" void kernel_launch(void* const* d_in, const int* in_sizes, int n_in,
                              void* d_out, int out_size, void* d_ws, size_t ws_size,
                              hipStream_t stream) {
    const float* x     = (const float*)d_in[0];
    const int*   ei    = (const int*)d_in[1];
    const int*   src   = ei;
    const int*   dst   = ei + N_EDGES;
    const float* W_gcn = (const float*)d_in[2];
    const float* b_gcn = (const float*)d_in[3];
    const float* Wm[8]; const float* Wl8[8];
    for (int i = 0; i < 8; ++i) { Wm[i] = (const float*)d_in[4 + i]; Wl8[i] = (const float*)d_in[12 + i]; }

    float* out    = (float*)d_out;
    float* mu_out = out;
    float* ls_out = out + N_NODES * D_DIM;

    float* ws   = (float*)d_ws;
    float* dinv = ws;                                          // N
    float* Mf   = dinv + N_NODES;                              // 2*128*128
    float* bpm  = Mf + 32768;                                  // 128
    float* bpl  = bpm + 128;                                   // 128
    unsigned short* hb  = (unsigned short*)(bpl + 128);        // N*128 bf16
    unsigned short* h0b = hb + (size_t)N_NODES * H_DIM;        // N*128 (-> Sbm)
    unsigned short* qmb = h0b + (size_t)N_NODES * H_DIM;       // N*128 (staging aliases)
    unsigned short* qlb = qmb + (size_t)N_NODES * H_DIM;       // N*128
    unsigned short* Sbl = qlb + (size_t)N_NODES * H_DIM;       // N*128
    unsigned short* wfg = Sbl + (size_t)N_NODES * H_DIM;       // 32768
    unsigned short* wfp = wfg + 32768;                         // 49152
    unsigned short* wfv = wfp + 49152;                         // 16384
    int* rowptr  = (int*)(wfv + 16384);           // N+4
    int* srcs    = rowptr + N_NODES + 4;          // E
    int* gCursor = srcs + N_EDGES;                // 256
    uint2* staging = (uint2*)qmb;                 // 7.84 MB, dead before k_qs
    unsigned short* Sbm = h0b;                    // h0b dead after gather

    const int B = 256;
    k_prepM<<<129, B, 0, stream>>>(Wm[0], Wm[2], Wm[1], Wl8[0], Wl8[2], Wl8[1],
                                   Mf, bpm, bpl);
    k_prep<<<385, B, 0, stream>>>(W_gcn, Mf, Wm[6], Wl8[6], Wm[4], Wl8[4],
                                  wfg, wfp, wfv, gCursor);
    k_bucketA<<<(N_EDGES + 4095) / 4096, B, 0, stream>>>(src, dst, gCursor, staging);
    k_bucketB<<<NB, B, 0, stream>>>(staging, gCursor, rowptr, dinv, srcs);

    // GCN
    k_gemm_gcn_mfma<<<GEMM_BLK, B, 0, stream>>>(x, wfg, dinv, h0b);
    k_gcn_gather<<<(N_NODES + 15) / 16, B, 0, stream>>>(h0b, rowptr, srcs, dinv, b_gcn, hb);

    // q' + skip GEMM (both convs), then h-gather attention, then Wv projection
    k_qs_mfma<<<GEMM_BLK, 384, 0, stream>>>(hb, wfp, bpm, bpl, Wm[7], Wl8[7],
                                            qmb, qlb, mu_out, ls_out);
    k_attn3<<<(N_NODES + 3) / 4, B, 0, stream>>>(qmb, qlb, hb, rowptr, srcs, Sbm, Sbl);
    k_proj<<<GEMM_BLK, B, 0, stream>>>(Sbm, Sbl, wfv, Wm[5], Wl8[5], rowptr,
                                       mu_out, ls_out);
}